// Round 1
// baseline (677.116 us; speedup 1.0000x reference)
//
#include <hip/hip_runtime.h>
#include <hip/hip_bf16.h>

#define T_IN   16
#define T_OUT  25
#define BHERO  4096
#define K_NBR  32
#define N_NBR  (BHERO * K_NBR)
#define ENC    64
#define DEC    128
#define DYN    32
#define EMB    32

__device__ __forceinline__ float lrelu(float x) { return x >= 0.f ? x : 0.1f * x; }
__device__ __forceinline__ float sigm(float x)  { return 1.f / (1.f + __expf(-x)); }
__device__ __forceinline__ float tanh_f(float x) {
    float e = __expf(-2.f * fabsf(x));        // in (0,1], no overflow
    float t = (1.f - e) / (1.f + e);
    return x >= 0.f ? t : -t;
}

// ---------------- Kernel 1: ego history encoder (LSTM hidden=64) ----------------
// One workgroup (256 threads) per hero. Thread r owns gate row r:
// Wih_e[r,0:32] + Whh_e[r,0:64] live in registers; h lives in LDS (broadcast reads).
__global__ __launch_bounds__(256) void ego_encoder_kernel(
    const float* __restrict__ hist,
    const float* __restrict__ Wip,  const float* __restrict__ bip,
    const float* __restrict__ Wih,  const float* __restrict__ Whh,
    const float* __restrict__ bih,  const float* __restrict__ bhh,
    const float* __restrict__ Wdyn, const float* __restrict__ bdyn,
    float* __restrict__ enc_out)                    // [BHERO][64], writes cols 0..31
{
    const int b = blockIdx.x;
    const int r = threadIdx.x;                      // gate row 0..255 (i,f,g,o blocks of 64)

    __shared__ __align__(16) float x_s[EMB];
    __shared__ __align__(16) float h_s[ENC];
    __shared__ float g_s[4 * ENC];

    float wih[EMB];
    {
        const float4* w4 = (const float4*)(Wih + (size_t)r * EMB);
        #pragma unroll
        for (int j = 0; j < EMB / 4; ++j) {
            float4 w = w4[j];
            wih[4*j+0] = w.x; wih[4*j+1] = w.y; wih[4*j+2] = w.z; wih[4*j+3] = w.w;
        }
    }
    float whh[ENC];
    {
        const float4* w4 = (const float4*)(Whh + (size_t)r * ENC);
        #pragma unroll
        for (int j = 0; j < ENC / 4; ++j) {
            float4 w = w4[j];
            whh[4*j+0] = w.x; whh[4*j+1] = w.y; whh[4*j+2] = w.z; whh[4*j+3] = w.w;
        }
    }
    const float bias = bih[r] + bhh[r];

    float wip0 = 0.f, wip1 = 0.f, bipv = 0.f;
    if (r < EMB) { wip0 = Wip[2*r]; wip1 = Wip[2*r + 1]; bipv = bip[r]; }
    if (r < ENC) h_s[r] = 0.f;
    float c = 0.f;                                   // cell state (threads r<64 only)
    __syncthreads();

    for (int t = 0; t < T_IN; ++t) {
        if (r < EMB) {
            float h0 = hist[((size_t)t * BHERO + b) * 2 + 0];
            float h1 = hist[((size_t)t * BHERO + b) * 2 + 1];
            x_s[r] = lrelu(fmaf(h0, wip0, fmaf(h1, wip1, bipv)));
        }
        __syncthreads();
        float a0 = 0.f, a1 = 0.f, a2 = 0.f, a3 = 0.f;
        #pragma unroll
        for (int j = 0; j < EMB; j += 4) {
            float4 xv = *(const float4*)&x_s[j];
            a0 = fmaf(wih[j+0], xv.x, a0);
            a1 = fmaf(wih[j+1], xv.y, a1);
            a2 = fmaf(wih[j+2], xv.z, a2);
            a3 = fmaf(wih[j+3], xv.w, a3);
        }
        #pragma unroll
        for (int j = 0; j < ENC; j += 4) {
            float4 hv = *(const float4*)&h_s[j];
            a0 = fmaf(whh[j+0], hv.x, a0);
            a1 = fmaf(whh[j+1], hv.y, a1);
            a2 = fmaf(whh[j+2], hv.z, a2);
            a3 = fmaf(whh[j+3], hv.w, a3);
        }
        g_s[r] = bias + ((a0 + a1) + (a2 + a3));
        __syncthreads();
        if (r < ENC) {
            float ig = g_s[r], fg = g_s[ENC + r], gg = g_s[2*ENC + r], og = g_s[3*ENC + r];
            c = sigm(fg) * c + sigm(ig) * tanh_f(gg);
            h_s[r] = sigm(og) * tanh_f(c);
        }
        __syncthreads();
    }

    // hist_e = lrelu(h_enc @ Wdyn.T + bdyn) -> enc_out cols 0..31
    if (r < DYN) {
        float a0 = 0.f, a1 = 0.f, a2 = 0.f, a3 = 0.f;
        #pragma unroll
        for (int j = 0; j < ENC; j += 4) {
            a0 = fmaf(Wdyn[r*ENC + j + 0], h_s[j + 0], a0);
            a1 = fmaf(Wdyn[r*ENC + j + 1], h_s[j + 1], a1);
            a2 = fmaf(Wdyn[r*ENC + j + 2], h_s[j + 2], a2);
            a3 = fmaf(Wdyn[r*ENC + j + 3], h_s[j + 3], a3);
        }
        enc_out[(size_t)b * (2*DYN) + r] = lrelu(bdyn[r] + ((a0 + a1) + (a2 + a3)));
    }
}

// ---------------- Kernel 2: neighbor scene (rela proj + segment max + proj) ----------------
// One workgroup (64 threads = 1 wave) per hero.
__global__ __launch_bounds__(64) void nbr_scene_kernel(
    const float* __restrict__ hist, const float* __restrict__ nbrs,
    const int*   __restrict__ seg,
    const float* __restrict__ Wnbr, const float* __restrict__ bnbr,
    const float* __restrict__ Wdyn, const float* __restrict__ bdyn,
    float* __restrict__ enc_out)                    // [BHERO][64], writes cols 32..63
{
    const int b   = blockIdx.x;
    const int tid = threadIdx.x;                    // 0..63

    __shared__ float rela_s[K_NBR][2 * T_IN + 1];   // +1 pad: kills 32-way write conflict
    __shared__ float scene_s[ENC];

    const int n0 = b * K_NBR;
    const int k  = tid >> 1, cch = tid & 1;
    const int hb = seg[n0 + k];                     // hero id via segment_ids (faithful gather)
    for (int t = 0; t < T_IN; ++t) {
        float hv = hist[((size_t)t * BHERO + hb) * 2 + cch];
        float nv = nbrs[((size_t)t * N_NBR + n0 + k) * 2 + cch];
        rela_s[k][2*t + cch] = hv - nv;
    }
    __syncthreads();

    float w[2 * T_IN];
    #pragma unroll
    for (int j = 0; j < 2 * T_IN; ++j) w[j] = Wnbr[tid * (2*T_IN) + j];
    const float bn = bnbr[tid];

    float m = -1e30f;
    for (int kk = 0; kk < K_NBR; ++kk) {
        float a0 = 0.f, a1 = 0.f, a2 = 0.f, a3 = 0.f;
        #pragma unroll
        for (int j = 0; j < 2 * T_IN; j += 4) {
            a0 = fmaf(w[j+0], rela_s[kk][j+0], a0);
            a1 = fmaf(w[j+1], rela_s[kk][j+1], a1);
            a2 = fmaf(w[j+2], rela_s[kk][j+2], a2);
            a3 = fmaf(w[j+3], rela_s[kk][j+3], a3);
        }
        m = fmaxf(m, lrelu(bn + ((a0 + a1) + (a2 + a3))));
    }
    scene_s[tid] = m;
    __syncthreads();

    if (tid < DYN) {
        float a0 = 0.f, a1 = 0.f, a2 = 0.f, a3 = 0.f;
        #pragma unroll
        for (int j = 0; j < ENC; j += 4) {
            a0 = fmaf(Wdyn[tid*ENC + j + 0], scene_s[j + 0], a0);
            a1 = fmaf(Wdyn[tid*ENC + j + 1], scene_s[j + 1], a1);
            a2 = fmaf(Wdyn[tid*ENC + j + 2], scene_s[j + 2], a2);
            a3 = fmaf(Wdyn[tid*ENC + j + 3], scene_s[j + 3], a3);
        }
        enc_out[(size_t)b * (2*DYN) + DYN + tid] = lrelu(bdyn[tid] + ((a0 + a1) + (a2 + a3)));
    }
}

// ---------------- Kernel 3: decoder LSTM (hidden=128, 25 steps) + output head ----------------
// One workgroup (512 threads) per TWO heroes; thread r owns gate row r (Whh_d row in
// 128 registers, reused for both heroes). Input is constant over steps -> xW precomputed.
__global__ __launch_bounds__(512) void decoder_kernel(
    const float* __restrict__ enc,                  // [BHERO][64]
    const float* __restrict__ Wih,  const float* __restrict__ Whh,
    const float* __restrict__ bih,  const float* __restrict__ bhh,
    const float* __restrict__ Wop,  const float* __restrict__ bop,
    float* __restrict__ fut)                        // [T_OUT][BHERO][2]
{
    const int b0 = blockIdx.x * 2;
    const int r  = threadIdx.x;                     // 0..511

    __shared__ __align__(16) float h_s[2][DEC];
    __shared__ float g_s[2][4 * DEC];
    __shared__ __align__(16) float enc_s[2][2 * DYN];
    __shared__ float red_s[4][2];

    if (r < 2 * (2*DYN)) enc_s[r >> 6][r & 63] = enc[(size_t)b0 * (2*DYN) + r];
    if (r < 2 * DEC)     h_s[r >> 7][r & 127] = 0.f;
    __syncthreads();

    float whh[DEC];
    {
        const float4* w4 = (const float4*)(Whh + (size_t)r * DEC);
        #pragma unroll
        for (int j = 0; j < DEC / 4; ++j) {
            float4 w = w4[j];
            whh[4*j+0] = w.x; whh[4*j+1] = w.y; whh[4*j+2] = w.z; whh[4*j+3] = w.w;
        }
    }
    const float bsum = bih[r] + bhh[r];
    float xw0 = bsum, xw1 = bsum;
    {
        const float4* w4 = (const float4*)(Wih + (size_t)r * (2*DYN));
        #pragma unroll
        for (int j = 0; j < (2*DYN) / 4; ++j) {
            float4 w  = w4[j];
            float4 e0 = *(const float4*)&enc_s[0][4*j];
            float4 e1 = *(const float4*)&enc_s[1][4*j];
            xw0 += w.x*e0.x + w.y*e0.y + w.z*e0.z + w.w*e0.w;
            xw1 += w.x*e1.x + w.y*e1.y + w.z*e1.z + w.w*e1.w;
        }
    }

    float c = 0.f;                                  // cell state (threads r<256: hero r>>7, unit r&127)
    float wop0 = 0.f, wop1 = 0.f;
    if (r < 2 * DEC) {
        int u = r & 127;
        wop0 = Wop[u];                              // Wop[0][u]
        wop1 = Wop[DEC + u];                        // Wop[1][u]
    }
    const float bop0 = bop[0], bop1 = bop[1];

    for (int t = 0; t < T_OUT; ++t) {
        float a00=0.f, a01=0.f, a02=0.f, a03=0.f;
        float a10=0.f, a11=0.f, a12=0.f, a13=0.f;
        #pragma unroll
        for (int j = 0; j < DEC; j += 4) {
            float4 h0 = *(const float4*)&h_s[0][j];
            float4 h1 = *(const float4*)&h_s[1][j];
            a00 = fmaf(whh[j+0], h0.x, a00);
            a01 = fmaf(whh[j+1], h0.y, a01);
            a02 = fmaf(whh[j+2], h0.z, a02);
            a03 = fmaf(whh[j+3], h0.w, a03);
            a10 = fmaf(whh[j+0], h1.x, a10);
            a11 = fmaf(whh[j+1], h1.y, a11);
            a12 = fmaf(whh[j+2], h1.z, a12);
            a13 = fmaf(whh[j+3], h1.w, a13);
        }
        g_s[0][r] = xw0 + ((a00 + a01) + (a02 + a03));
        g_s[1][r] = xw1 + ((a10 + a11) + (a12 + a13));
        __syncthreads();                            // g ready; also orders next-iter g writes after g reads
        if (r < 2 * DEC) {
            const int hh = r >> 7, u = r & 127;
            float ig = g_s[hh][u], fg = g_s[hh][DEC + u];
            float gg = g_s[hh][2*DEC + u], og = g_s[hh][3*DEC + u];
            c = sigm(fg) * c + sigm(ig) * tanh_f(gg);
            float h = sigm(og) * tanh_f(c);
            h_s[hh][u] = h;
            // fused output head: fut[t,hero,:] = h @ Wop.T + bop (shuffle-reduce over the wave)
            float p0 = wop0 * h, p1 = wop1 * h;
            #pragma unroll
            for (int off = 32; off > 0; off >>= 1) {
                p0 += __shfl_down(p0, off);
                p1 += __shfl_down(p1, off);
            }
            if ((r & 63) == 0) { red_s[r >> 6][0] = p0; red_s[r >> 6][1] = p1; }
        }
        __syncthreads();                            // h + red ready for next iter / output
        if (r < 2) {
            float o0 = red_s[2*r][0] + red_s[2*r + 1][0] + bop0;
            float o1 = red_s[2*r][1] + red_s[2*r + 1][1] + bop1;
            float* dst = fut + ((size_t)t * BHERO + b0 + r) * 2;
            dst[0] = o0; dst[1] = o1;
            // no extra barrier needed: next iteration's red_s writes are ordered
            // after this read by the next iteration's first __syncthreads().
        }
    }
}

extern "C" void kernel_launch(void* const* d_in, const int* in_sizes, int n_in,
                              void* d_out, int out_size, void* d_ws, size_t ws_size,
                              hipStream_t stream) {
    const float* hist  = (const float*)d_in[0];
    const float* nbrs  = (const float*)d_in[1];
    const float* Wip   = (const float*)d_in[2];
    const float* bip   = (const float*)d_in[3];
    const float* Wih_e = (const float*)d_in[4];
    const float* Whh_e = (const float*)d_in[5];
    const float* bih_e = (const float*)d_in[6];
    const float* bhh_e = (const float*)d_in[7];
    const float* Wdyn  = (const float*)d_in[8];
    const float* bdyn  = (const float*)d_in[9];
    const float* Wnbr  = (const float*)d_in[10];
    const float* bnbr  = (const float*)d_in[11];
    const float* Wih_d = (const float*)d_in[12];
    const float* Whh_d = (const float*)d_in[13];
    const float* bih_d = (const float*)d_in[14];
    const float* bhh_d = (const float*)d_in[15];
    const float* Wop   = (const float*)d_in[16];
    const float* bop   = (const float*)d_in[17];
    const int*   seg   = (const int*)d_in[18];

    float* fut    = (float*)d_out;
    float* enc_ws = (float*)d_ws;                   // [BHERO][64] = 1 MB scratch

    hipLaunchKernelGGL(ego_encoder_kernel, dim3(BHERO), dim3(256), 0, stream,
                       hist, Wip, bip, Wih_e, Whh_e, bih_e, bhh_e, Wdyn, bdyn, enc_ws);
    hipLaunchKernelGGL(nbr_scene_kernel, dim3(BHERO), dim3(64), 0, stream,
                       hist, nbrs, seg, Wnbr, bnbr, Wdyn, bdyn, enc_ws);
    hipLaunchKernelGGL(decoder_kernel, dim3(BHERO / 2), dim3(512), 0, stream,
                       enc_ws, Wih_d, Whh_d, bih_d, bhh_d, Wop, bop, fut);
}